// Round 3
// baseline (4865.794 us; speedup 1.0000x reference)
//
#include <hip/hip_runtime.h>
#include <hip/hip_bf16.h>

// Problem constants
#define B_   64
#define T_   512
#define EMB_ 256
#define H_   256          // hidden per direction
#define L_   9
#define NROW (B_*T_)      // 32768
#define NG   2048         // both directions' gates

typedef __attribute__((ext_vector_type(8))) short bf16x8;
typedef __attribute__((ext_vector_type(4))) float f32x4;

__device__ __forceinline__ float bf2f(unsigned short u) {
    union { unsigned int i; float f; } c; c.i = ((unsigned int)u) << 16; return c.f;
}
__device__ __forceinline__ unsigned short f2bf(float f) {
    union { unsigned int i; float f; } c; c.f = f;
    unsigned int i = c.i;
    unsigned int r = (i + 0x7FFFu + ((i >> 16) & 1u)) >> 16;
    return (unsigned short)r;
}
__device__ __forceinline__ float sigmf(float x) { return 1.0f / (1.0f + __expf(-x)); }
__device__ __forceinline__ float tanh_fast(float x) {
    return 2.0f / (1.0f + __expf(-2.0f * x)) - 1.0f;
}

// ---------------------------------------------------------------------------
// bias[n] = b_ih + b_hh (both dirs)
// ---------------------------------------------------------------------------
__global__ void __launch_bounds__(256) bias_k(
    const float* __restrict__ bihf, const float* __restrict__ bhhf,
    const float* __restrict__ bihb, const float* __restrict__ bhhb,
    float* __restrict__ bias)
{
    int i = blockIdx.x * 256 + threadIdx.x;   // 0..2047
    if (i < 1024) bias[i] = bihf[i] + bhhf[i];
    else          bias[i] = bihb[i - 1024] + bhhb[i - 1024];
}

__global__ void __launch_bounds__(256) zero_flags(int* __restrict__ cnt)
{
    cnt[blockIdx.x * 256 + threadIdx.x] = 0;   // 16 blocks -> 4096 ints
}

// ---------------------------------------------------------------------------
// xg GEMM: xg[row][n] = sum_k emb[ids[row]][k] * w(n)[k] + bias[n]  (bf16 out)
// ---------------------------------------------------------------------------
#define BM 128
#define BN 128
#define BK 16
__global__ void __launch_bounds__(256) xg_gemm(
    const float* __restrict__ emb, const int* __restrict__ ids,
    const float* __restrict__ w_f, const float* __restrict__ w_b,
    const float* __restrict__ bias, unsigned short* __restrict__ xg)
{
    __shared__ float As[BK][BM];
    __shared__ float Bs[BK][BN];
    __shared__ int rowtok[BM];
    int tid = threadIdx.x;
    int row0 = blockIdx.x * BM;
    int col0 = blockIdx.y * BN;
    if (tid < BM) rowtok[tid] = ids[row0 + tid];
    __syncthreads();

    int tx = tid & 15, ty = tid >> 4;
    float acc[8][8];
#pragma unroll
    for (int i = 0; i < 8; ++i)
#pragma unroll
        for (int j = 0; j < 8; ++j) acc[i][j] = 0.0f;

    for (int k0 = 0; k0 < EMB_; k0 += BK) {
#pragma unroll
        for (int l = 0; l < 2; ++l) {
            int idx = tid + l * 256;
            int r  = idx >> 2;
            int kc = (idx & 3) * 4;
            const float* src = emb + (size_t)rowtok[r] * EMB_ + k0 + kc;
            float4 v = *(const float4*)src;
            As[kc + 0][r] = v.x; As[kc + 1][r] = v.y;
            As[kc + 2][r] = v.z; As[kc + 3][r] = v.w;
        }
#pragma unroll
        for (int l = 0; l < 2; ++l) {
            int idx = tid + l * 256;
            int c  = idx >> 2;
            int kc = (idx & 3) * 4;
            int n  = col0 + c;
            const float* wr = (n < 1024) ? (w_f + (size_t)n * EMB_)
                                         : (w_b + (size_t)(n - 1024) * EMB_);
            float4 v = *(const float4*)(wr + k0 + kc);
            Bs[kc + 0][c] = v.x; Bs[kc + 1][c] = v.y;
            Bs[kc + 2][c] = v.z; Bs[kc + 3][c] = v.w;
        }
        __syncthreads();
#pragma unroll
        for (int k = 0; k < BK; ++k) {
            float a[8], b[8];
            *(float4*)&a[0] = *(float4*)&As[k][ty * 8];
            *(float4*)&a[4] = *(float4*)&As[k][ty * 8 + 4];
            *(float4*)&b[0] = *(float4*)&Bs[k][tx * 8];
            *(float4*)&b[4] = *(float4*)&Bs[k][tx * 8 + 4];
#pragma unroll
            for (int i = 0; i < 8; ++i)
#pragma unroll
                for (int j = 0; j < 8; ++j) acc[i][j] += a[i] * b[j];
        }
        __syncthreads();
    }
#pragma unroll
    for (int i = 0; i < 8; ++i) {
        size_t row = (size_t)row0 + ty * 8 + i;
#pragma unroll
        for (int j4 = 0; j4 < 2; ++j4) {
            int nb = col0 + tx * 8 + j4 * 4;
            ushort4 o;
            o.x = f2bf(acc[i][j4 * 4 + 0] + bias[nb + 0]);
            o.y = f2bf(acc[i][j4 * 4 + 1] + bias[nb + 1]);
            o.z = f2bf(acc[i][j4 * 4 + 2] + bias[nb + 2]);
            o.w = f2bf(acc[i][j4 * 4 + 3] + bias[nb + 3]);
            *(ushort4*)(xg + row * NG + nb) = o;
        }
    }
}

// ---------------------------------------------------------------------------
// Persistent cluster LSTM with register-resident weights + MFMA.
// 128 blocks x 256 threads. cluster = bid & 7 (one per (dir, 16-batch group));
// 16 blocks per cluster, block owns 16 h-dims (4 gate types x 16 rows).
// Per step: gates[16b x 16j] per gate-type wave via 8x mfma_16x16x32_bf16,
// cross-wave combine in LDS, lane-local cell update, h published as packed
// bf16 pairs via agent-scope atomics (double-buffered by step parity),
// cluster counter flag sync.
// ---------------------------------------------------------------------------
__global__ void __launch_bounds__(256) lstm_mfma(
    const unsigned short* __restrict__ xg,
    const float* __restrict__ w_hh_f, const float* __restrict__ w_hh_b,
    float* __restrict__ h_all,
    unsigned int* __restrict__ h_cur,   // [2 parity][8 cluster][16 b][128] uint
    int* __restrict__ cnt)              // [8 cluster][512 step]
{
    const int bid = blockIdx.x;
    const int cluster = bid & 7;
    const int blk = bid >> 3;            // 0..15
    const int dir = cluster >> 2;
    const int bbase = (cluster & 3) * 16;
    const int j0 = blk * 16;
    const int tid = threadIdx.x;
    const int w = tid >> 6;              // gate type: 0=i 1=f 2=g 3=o
    const int l = tid & 63;
    const int l15 = l & 15, lq = l >> 4;

    const float* whh = dir ? w_hh_b : w_hh_f;

    // One-time B fragments (weights, stationary in registers).
    // B[k][n]: n = j0 + l15 (h-dim), k = kt*32 + lq*8 + e.
    bf16x8 bfrag[8];
    {
        const float* wr = whh + ((size_t)(w * 256 + j0 + l15)) * 256;
#pragma unroll
        for (int kt = 0; kt < 8; ++kt) {
            bf16x8 f;
#pragma unroll
            for (int e = 0; e < 8; ++e)
                f[e] = (short)f2bf(wr[kt * 32 + lq * 8 + e]);
            bfrag[kt] = f;
        }
    }

    __shared__ float gate_lds[4][256];
    unsigned int* hc0 = h_cur + cluster * 2048;             // parity 0
    unsigned int* hc1 = h_cur + 8 * 2048 + cluster * 2048;  // parity 1
    int* mycnt = cnt + cluster * 512;

    float c = 0.0f;                       // cell state for (b=tid>>4, j=j0+(tid&15))
    const int ub = tid >> 4, uj = tid & 15;

    for (int s = 0; s < T_; ++s) {
        const int t = dir ? (T_ - 1 - s) : s;

        // acc init from xg (C/D layout: row=batch=(lq*4+r), col=j=l15).
        // Issued before the spin so HBM latency overlaps the wait.
        f32x4 acc;
#pragma unroll
        for (int r = 0; r < 4; ++r) {
            size_t row = (size_t)(bbase + lq * 4 + r) * T_ + t;
            acc[r] = bf2f(xg[row * NG + dir * 1024 + w * 256 + j0 + l15]);
        }

        if (s > 0) {
            if (tid == 0) {
                while (__hip_atomic_load(&mycnt[s - 1], __ATOMIC_ACQUIRE,
                                         __HIP_MEMORY_SCOPE_AGENT) < 16)
                    __builtin_amdgcn_s_sleep(2);
            }
            __syncthreads();
            const unsigned int* hb = (s & 1) ? hc0 : hc1;   // parity of s-1
#pragma unroll
            for (int kt = 0; kt < 8; ++kt) {
                const unsigned int* p = hb + l15 * 128 + kt * 16 + lq * 4;
                union { unsigned int u[4]; bf16x8 v; } af;
                af.u[0] = __hip_atomic_load(p + 0, __ATOMIC_RELAXED, __HIP_MEMORY_SCOPE_AGENT);
                af.u[1] = __hip_atomic_load(p + 1, __ATOMIC_RELAXED, __HIP_MEMORY_SCOPE_AGENT);
                af.u[2] = __hip_atomic_load(p + 2, __ATOMIC_RELAXED, __HIP_MEMORY_SCOPE_AGENT);
                af.u[3] = __hip_atomic_load(p + 3, __ATOMIC_RELAXED, __HIP_MEMORY_SCOPE_AGENT);
                acc = __builtin_amdgcn_mfma_f32_16x16x32_bf16(af.v, bfrag[kt], acc, 0, 0, 0);
            }
        }

        // publish gate tile to LDS: gate_lds[w][b*16 + j]
#pragma unroll
        for (int r = 0; r < 4; ++r)
            gate_lds[w][(lq * 4 + r) * 16 + l15] = acc[r];
        __syncthreads();

        float gi = gate_lds[0][tid];
        float gf = gate_lds[1][tid];
        float gg = gate_lds[2][tid];
        float go = gate_lds[3][tid];
        c = sigmf(gf) * c + sigmf(gi) * tanh_fast(gg);
        float h = sigmf(go) * tanh_fast(c);
        h_all[(((size_t)dir * B_ + bbase + ub) * T_ + t) * H_ + j0 + uj] = h;

        // pack (even j, odd j) bf16 pair, publish device-visible
        unsigned int me = f2bf(h);
        unsigned int nb = __shfl_down(me, 1);
        if (!(uj & 1)) {
            unsigned int pw = me | (nb << 16);
            unsigned int* hw = (s & 1) ? hc1 : hc0;
            __hip_atomic_store(&hw[ub * 128 + ((j0 + uj) >> 1)], pw,
                               __ATOMIC_RELAXED, __HIP_MEMORY_SCOPE_AGENT);
        }
        __syncthreads();   // drains vmcnt: all h stores device-visible (sc-flagged)
        if (tid == 0)
            __hip_atomic_fetch_add(&mycnt[s], 1, __ATOMIC_RELEASE,
                                   __HIP_MEMORY_SCOPE_AGENT);
    }
}

// ---------------------------------------------------------------------------
// Emissions
// ---------------------------------------------------------------------------
__global__ void __launch_bounds__(256) emis_k(
    const float* __restrict__ h_all, const float* __restrict__ w_cls,
    const float* __restrict__ b_cls, float* __restrict__ em)
{
    int wid = threadIdx.x >> 6, lane = threadIdx.x & 63;
    size_t row = (size_t)blockIdx.x * 4 + wid;
    const float* hf = h_all + row * H_;
    const float* hb = h_all + (size_t)B_ * T_ * H_ + row * H_;
    float4 a0 = *(const float4*)(hf + 4 * lane);
    float4 a1 = *(const float4*)(hb + 4 * lane);
#pragma unroll
    for (int l = 0; l < L_; ++l) {
        const float* wr = w_cls + (size_t)l * 512;
        float4 w0 = *(const float4*)(wr + 4 * lane);
        float4 w1 = *(const float4*)(wr + 256 + 4 * lane);
        float d = a0.x * w0.x + a0.y * w0.y + a0.z * w0.z + a0.w * w0.w
                + a1.x * w1.x + a1.y * w1.y + a1.z * w1.z + a1.w * w1.w;
#pragma unroll
        for (int off = 32; off; off >>= 1) d += __shfl_down(d, off);
        if (lane == 0) em[row * L_ + l] = d + b_cls[l];
    }
}

// ---------------------------------------------------------------------------
// CRF NLL
// ---------------------------------------------------------------------------
__global__ void __launch_bounds__(64) crf_k(
    const float* __restrict__ em, const int* __restrict__ labels,
    const int* __restrict__ mask, const float* __restrict__ trans,
    const float* __restrict__ startv, const float* __restrict__ endv,
    float* __restrict__ out)
{
    int b = blockIdx.x, lane = threadIdx.x;
    const float* emb_ = em + (size_t)b * T_ * L_;
    const int* lab = labels + (size_t)b * T_;
    const int* msk = mask + (size_t)b * T_;
    __shared__ float alpha[L_];
    __shared__ float trs[81];
    for (int i = lane; i < 81; i += 64) trs[i] = trans[i];
    __syncthreads();

    float np = 0.0f;
    for (int t = 1 + lane; t < T_; t += 64)
        if (msk[t]) np += trs[lab[t - 1] * L_ + lab[t]] + emb_[(size_t)t * L_ + lab[t]];
    int mc = 0;
    for (int t = lane; t < T_; t += 64) mc += (msk[t] != 0);
#pragma unroll
    for (int off = 32; off; off >>= 1) {
        np += __shfl_down(np, off);
        mc += __shfl_down(mc, off);
    }
    float num = 0.0f;
    if (lane == 0) {
        int last = mc - 1;
        num = np + startv[lab[0]] + emb_[lab[0]] + endv[lab[last]];
    }

    if (lane < L_) alpha[lane] = startv[lane] + emb_[lane];
    __syncthreads();
    for (int t = 1; t < T_; ++t) {
        float na = 0.0f;
        if (lane < L_) {
            float m = -1e30f;
#pragma unroll
            for (int i = 0; i < L_; ++i) m = fmaxf(m, alpha[i] + trs[i * L_ + lane]);
            float s = 0.0f;
#pragma unroll
            for (int i = 0; i < L_; ++i) s += __expf(alpha[i] + trs[i * L_ + lane] - m);
            na = m + __logf(s) + emb_[(size_t)t * L_ + lane];
            if (!msk[t]) na = alpha[lane];
        }
        __syncthreads();
        if (lane < L_) alpha[lane] = na;
        __syncthreads();
    }
    float v = (lane < L_) ? alpha[lane] + endv[lane] : -1e30f;
    float m = v;
#pragma unroll
    for (int off = 32; off; off >>= 1) m = fmaxf(m, __shfl_xor(m, off));
    float s = (lane < L_) ? __expf(v - m) : 0.0f;
#pragma unroll
    for (int off = 32; off; off >>= 1) s += __shfl_xor(s, off);
    if (lane == 0) {
        float logZ = m + __logf(s);
        atomicAdd(out, (logZ - num) / (float)B_);
    }
}

__global__ void zero_out_k(float* out) { out[0] = 0.0f; }
__global__ void ws_fail_k(float* out, float v) { out[0] = v; }

// ---------------------------------------------------------------------------
extern "C" void kernel_launch(void* const* d_in, const int* in_sizes, int n_in,
                              void* d_out, int out_size, void* d_ws, size_t ws_size,
                              hipStream_t stream)
{
    const int*   ids    = (const int*)  d_in[0];
    const int*   amask  = (const int*)  d_in[1];
    const int*   labels = (const int*)  d_in[2];
    const float* emb    = (const float*)d_in[3];
    const float* w_ih_f = (const float*)d_in[4];
    const float* w_hh_f = (const float*)d_in[5];
    const float* b_ih_f = (const float*)d_in[6];
    const float* b_hh_f = (const float*)d_in[7];
    const float* w_ih_b = (const float*)d_in[8];
    const float* w_hh_b = (const float*)d_in[9];
    const float* b_ih_b = (const float*)d_in[10];
    const float* b_hh_b = (const float*)d_in[11];
    const float* w_cls  = (const float*)d_in[12];
    const float* b_cls  = (const float*)d_in[13];
    const float* trans  = (const float*)d_in[14];
    const float* startv = (const float*)d_in[15];
    const float* endv   = (const float*)d_in[16];
    float* out = (float*)d_out;

    // workspace layout
    size_t o_xg   = 0;                                   // bf16 xg: 128 MB
    size_t o_bias = o_xg + (size_t)NROW * NG * 2;
    size_t o_h    = o_bias + 2048 * 4;
    size_t o_em   = o_h + (size_t)2 * B_ * T_ * H_ * 4;  // 64 MB
    size_t o_hc   = o_em + (size_t)NROW * L_ * 4;
    size_t o_cnt  = o_hc + (size_t)2 * 8 * 2048 * 4;     // h_cur 128 KB
    size_t total  = o_cnt + (size_t)8 * 512 * 4;         // cnt 16 KB

    if (ws_size < total) {
        ws_fail_k<<<1, 1, 0, stream>>>(out, -1.0e8f - (float)(ws_size >> 20));
        return;
    }

    unsigned short* xg   = (unsigned short*)((char*)d_ws + o_xg);
    float* bias          = (float*)((char*)d_ws + o_bias);
    float* h_all         = (float*)((char*)d_ws + o_h);
    float* em            = (float*)((char*)d_ws + o_em);
    unsigned int* h_cur  = (unsigned int*)((char*)d_ws + o_hc);
    int* cnt             = (int*)((char*)d_ws + o_cnt);

    bias_k<<<8, 256, 0, stream>>>(b_ih_f, b_hh_f, b_ih_b, b_hh_b, bias);
    zero_flags<<<16, 256, 0, stream>>>(cnt);
    xg_gemm<<<dim3(NROW / BM, NG / BN), 256, 0, stream>>>(emb, ids, w_ih_f, w_ih_b, bias, xg);
    lstm_mfma<<<128, 256, 0, stream>>>(xg, w_hh_f, w_hh_b, h_all, h_cur, cnt);
    emis_k<<<NROW / 4, 256, 0, stream>>>(h_all, w_cls, b_cls, em);
    zero_out_k<<<1, 1, 0, stream>>>(out);
    crf_k<<<B_, 64, 0, stream>>>(em, labels, amask, trans, startv, endv, out);
}

// Round 4
// 2704.643 us; speedup vs baseline: 1.7991x; 1.7991x over previous
//
#include <hip/hip_runtime.h>
#include <hip/hip_bf16.h>

// Problem constants
#define B_   64
#define T_   512
#define EMB_ 256
#define H_   256          // hidden per direction
#define L_   9
#define NROW (B_*T_)      // 32768
#define NG   2048         // both directions' gates

typedef __attribute__((ext_vector_type(8))) short bf16x8;
typedef __attribute__((ext_vector_type(4))) float f32x4;

__device__ __forceinline__ float bf2f(unsigned short u) {
    union { unsigned int i; float f; } c; c.i = ((unsigned int)u) << 16; return c.f;
}
__device__ __forceinline__ unsigned short f2bf(float f) {
    union { unsigned int i; float f; } c; c.f = f;
    unsigned int i = c.i;
    unsigned int r = (i + 0x7FFFu + ((i >> 16) & 1u)) >> 16;
    return (unsigned short)r;
}
__device__ __forceinline__ float sigmf(float x) { return 1.0f / (1.0f + __expf(-x)); }
__device__ __forceinline__ float tanh_fast(float x) {
    return 2.0f / (1.0f + __expf(-2.0f * x)) - 1.0f;
}

// ---------------------------------------------------------------------------
// bias[n] = b_ih + b_hh (both dirs)
// ---------------------------------------------------------------------------
__global__ void __launch_bounds__(256) bias_k(
    const float* __restrict__ bihf, const float* __restrict__ bhhf,
    const float* __restrict__ bihb, const float* __restrict__ bhhb,
    float* __restrict__ bias)
{
    int i = blockIdx.x * 256 + threadIdx.x;   // 0..2047
    if (i < 1024) bias[i] = bihf[i] + bhhf[i];
    else          bias[i] = bihb[i - 1024] + bhhb[i - 1024];
}

__global__ void __launch_bounds__(256) zero_flags(int* __restrict__ cnt)
{
    cnt[blockIdx.x * 256 + threadIdx.x] = 0;   // 16 blocks -> 4096 ints
}

// ---------------------------------------------------------------------------
// xg GEMM: xg[row][n] = sum_k emb[ids[row]][k] * w(n)[k] + bias[n]  (bf16 out)
// ---------------------------------------------------------------------------
#define BM 128
#define BN 128
#define BK 16
__global__ void __launch_bounds__(256) xg_gemm(
    const float* __restrict__ emb, const int* __restrict__ ids,
    const float* __restrict__ w_f, const float* __restrict__ w_b,
    const float* __restrict__ bias, unsigned short* __restrict__ xg)
{
    __shared__ float As[BK][BM];
    __shared__ float Bs[BK][BN];
    __shared__ int rowtok[BM];
    int tid = threadIdx.x;
    int row0 = blockIdx.x * BM;
    int col0 = blockIdx.y * BN;
    if (tid < BM) rowtok[tid] = ids[row0 + tid];
    __syncthreads();

    int tx = tid & 15, ty = tid >> 4;
    float acc[8][8];
#pragma unroll
    for (int i = 0; i < 8; ++i)
#pragma unroll
        for (int j = 0; j < 8; ++j) acc[i][j] = 0.0f;

    for (int k0 = 0; k0 < EMB_; k0 += BK) {
#pragma unroll
        for (int l = 0; l < 2; ++l) {
            int idx = tid + l * 256;
            int r  = idx >> 2;
            int kc = (idx & 3) * 4;
            const float* src = emb + (size_t)rowtok[r] * EMB_ + k0 + kc;
            float4 v = *(const float4*)src;
            As[kc + 0][r] = v.x; As[kc + 1][r] = v.y;
            As[kc + 2][r] = v.z; As[kc + 3][r] = v.w;
        }
#pragma unroll
        for (int l = 0; l < 2; ++l) {
            int idx = tid + l * 256;
            int c  = idx >> 2;
            int kc = (idx & 3) * 4;
            int n  = col0 + c;
            const float* wr = (n < 1024) ? (w_f + (size_t)n * EMB_)
                                         : (w_b + (size_t)(n - 1024) * EMB_);
            float4 v = *(const float4*)(wr + k0 + kc);
            Bs[kc + 0][c] = v.x; Bs[kc + 1][c] = v.y;
            Bs[kc + 2][c] = v.z; Bs[kc + 3][c] = v.w;
        }
        __syncthreads();
#pragma unroll
        for (int k = 0; k < BK; ++k) {
            float a[8], b[8];
            *(float4*)&a[0] = *(float4*)&As[k][ty * 8];
            *(float4*)&a[4] = *(float4*)&As[k][ty * 8 + 4];
            *(float4*)&b[0] = *(float4*)&Bs[k][tx * 8];
            *(float4*)&b[4] = *(float4*)&Bs[k][tx * 8 + 4];
#pragma unroll
            for (int i = 0; i < 8; ++i)
#pragma unroll
                for (int j = 0; j < 8; ++j) acc[i][j] += a[i] * b[j];
        }
        __syncthreads();
    }
#pragma unroll
    for (int i = 0; i < 8; ++i) {
        size_t row = (size_t)row0 + ty * 8 + i;
#pragma unroll
        for (int j4 = 0; j4 < 2; ++j4) {
            int nb = col0 + tx * 8 + j4 * 4;
            ushort4 o;
            o.x = f2bf(acc[i][j4 * 4 + 0] + bias[nb + 0]);
            o.y = f2bf(acc[i][j4 * 4 + 1] + bias[nb + 1]);
            o.z = f2bf(acc[i][j4 * 4 + 2] + bias[nb + 2]);
            o.w = f2bf(acc[i][j4 * 4 + 3] + bias[nb + 3]);
            *(ushort4*)(xg + row * NG + nb) = o;
        }
    }
}

// ---------------------------------------------------------------------------
// Persistent cluster LSTM, register-resident weights + MFMA.
// 32 blocks x 256 threads. cluster = bid & 7 = (dir, 16-batch group);
// 4 blocks per cluster, block owns 64 h-dims (x 4 gate types = 256 gate rows,
// 128 KB bf16 weights in 128 VGPRs/thread of B-fragments).
// All cross-block traffic via RELAXED agent-scope atomics (cache-bypassing,
// no acquire/release cache-maintenance). Ordering: __syncthreads vmcnt-drain
// before the flag add; barrier after the spin before the h loads.
// h_cur double-buffered by step parity (legal: flag[s]==4 implies all blocks
// finished their step-s reads, so step-s+1 writes to the s-1 buffer are safe).
// ---------------------------------------------------------------------------
__global__ void __launch_bounds__(256, 1) lstm_mfma(
    const unsigned short* __restrict__ xg,
    const float* __restrict__ w_hh_f, const float* __restrict__ w_hh_b,
    float* __restrict__ h_all,
    unsigned long long* __restrict__ h_cur, // [2 parity][8 cluster][16 b][64] ull
    int* __restrict__ cnt)                  // [8 cluster][512 step]
{
    const int bid = blockIdx.x;      // 0..31
    const int cluster = bid & 7;
    const int blk = bid >> 3;        // 0..3
    const int dir = cluster >> 2;
    const int bbase = (cluster & 3) * 16;
    const int j0 = blk * 64;
    const int tid = threadIdx.x;
    const int w = tid >> 6;          // gate type: 0=i 1=f 2=g 3=o
    const int l = tid & 63;
    const int l15 = l & 15, lq = l >> 4;

    const float* whh = dir ? w_hh_b : w_hh_f;

    // Stationary B fragments: B[k][n], n = j0 + nt*16 + l15, k = kt*32 + lq*8 + e.
    bf16x8 bfrag[4][8];
#pragma unroll
    for (int nt = 0; nt < 4; ++nt) {
        const float* wr = whh + (size_t)(w * 256 + j0 + nt * 16 + l15) * 256;
#pragma unroll
        for (int kt = 0; kt < 8; ++kt) {
            bf16x8 f;
#pragma unroll
            for (int e = 0; e < 8; ++e)
                f[e] = (short)f2bf(wr[kt * 32 + lq * 8 + e]);
            bfrag[nt][kt] = f;
        }
    }

    __shared__ float gate_lds[4][16 * 66];   // padded stride 66
    unsigned long long* hc0 = h_cur + (size_t)cluster * 1024;
    unsigned long long* hc1 = h_cur + 8 * 1024 + (size_t)cluster * 1024;
    int* mycnt = cnt + cluster * 512;

    // Thread-stationary cell state: (b = bbase + ub, j = j0 + jj0 + q)
    const int ub = tid >> 4, jj0 = (tid & 15) * 4;
    float cst[4] = {0.f, 0.f, 0.f, 0.f};

    for (int s = 0; s < T_; ++s) {
        const int t = dir ? (T_ - 1 - s) : s;

        // acc init from xg (C/D: row=batch=lq*4+r, col=l15). Issued before the
        // spin so HBM latency overlaps the wait.
        f32x4 acc[4];
#pragma unroll
        for (int nt = 0; nt < 4; ++nt)
#pragma unroll
            for (int r = 0; r < 4; ++r) {
                size_t row = (size_t)(bbase + lq * 4 + r) * T_ + t;
                acc[nt][r] = bf2f(xg[row * NG + dir * 1024 + w * 256 + j0 + nt * 16 + l15]);
            }

        if (s > 0) {
            if (tid == 0) {
                while (__hip_atomic_load(&mycnt[s - 1], __ATOMIC_RELAXED,
                                         __HIP_MEMORY_SCOPE_AGENT) < 4)
                    __builtin_amdgcn_s_sleep(1);
            }
            __syncthreads();
            const unsigned long long* hb = (s & 1) ? hc0 : hc1;   // parity of s-1
            bf16x8 af[8];
#pragma unroll
            for (int kt = 0; kt < 8; ++kt) {
                const unsigned long long* p = hb + l15 * 64 + kt * 8 + lq * 2;
                union { unsigned long long u[2]; bf16x8 v; } a;
                a.u[0] = __hip_atomic_load(p + 0, __ATOMIC_RELAXED, __HIP_MEMORY_SCOPE_AGENT);
                a.u[1] = __hip_atomic_load(p + 1, __ATOMIC_RELAXED, __HIP_MEMORY_SCOPE_AGENT);
                af[kt] = a.v;
            }
#pragma unroll
            for (int nt = 0; nt < 4; ++nt)
#pragma unroll
                for (int kt = 0; kt < 8; ++kt)
                    acc[nt] = __builtin_amdgcn_mfma_f32_16x16x32_bf16(
                        af[kt], bfrag[nt][kt], acc[nt], 0, 0, 0);
        }

        // publish gate tile: gate_lds[w][b*66 + jlocal]
#pragma unroll
        for (int nt = 0; nt < 4; ++nt)
#pragma unroll
            for (int r = 0; r < 4; ++r)
                gate_lds[w][(lq * 4 + r) * 66 + nt * 16 + l15] = acc[nt][r];
        __syncthreads();

        // cell update: 4 h-values per thread
        float hv[4];
#pragma unroll
        for (int q = 0; q < 4; ++q) {
            int a = ub * 66 + jj0 + q;
            float gi = gate_lds[0][a];
            float gf = gate_lds[1][a];
            float gg = gate_lds[2][a];
            float go = gate_lds[3][a];
            cst[q] = sigmf(gf) * cst[q] + sigmf(gi) * tanh_fast(gg);
            hv[q] = sigmf(go) * tanh_fast(cst[q]);
        }
        *(float4*)&h_all[(((size_t)dir * B_ + bbase + ub) * T_ + t) * H_ + j0 + jj0] =
            make_float4(hv[0], hv[1], hv[2], hv[3]);

        // pack 4 bf16 -> one 8-byte relaxed agent store (cache-bypassing)
        unsigned int lo = (unsigned int)f2bf(hv[0]) | ((unsigned int)f2bf(hv[1]) << 16);
        unsigned int hi = (unsigned int)f2bf(hv[2]) | ((unsigned int)f2bf(hv[3]) << 16);
        unsigned long long pw = (unsigned long long)lo | ((unsigned long long)hi << 32);
        unsigned long long* hw = (s & 1) ? hc1 : hc0;
        __hip_atomic_store(&hw[ub * 64 + ((j0 + jj0) >> 2)], pw,
                           __ATOMIC_RELAXED, __HIP_MEMORY_SCOPE_AGENT);
        __syncthreads();   // vmcnt(0) drain: h stores at MALL before flag
        if (tid == 0)
            __hip_atomic_fetch_add(&mycnt[s], 1, __ATOMIC_RELAXED,
                                   __HIP_MEMORY_SCOPE_AGENT);
    }
}

// ---------------------------------------------------------------------------
// Emissions
// ---------------------------------------------------------------------------
__global__ void __launch_bounds__(256) emis_k(
    const float* __restrict__ h_all, const float* __restrict__ w_cls,
    const float* __restrict__ b_cls, float* __restrict__ em)
{
    int wid = threadIdx.x >> 6, lane = threadIdx.x & 63;
    size_t row = (size_t)blockIdx.x * 4 + wid;
    const float* hf = h_all + row * H_;
    const float* hb = h_all + (size_t)B_ * T_ * H_ + row * H_;
    float4 a0 = *(const float4*)(hf + 4 * lane);
    float4 a1 = *(const float4*)(hb + 4 * lane);
#pragma unroll
    for (int l = 0; l < L_; ++l) {
        const float* wr = w_cls + (size_t)l * 512;
        float4 w0 = *(const float4*)(wr + 4 * lane);
        float4 w1 = *(const float4*)(wr + 256 + 4 * lane);
        float d = a0.x * w0.x + a0.y * w0.y + a0.z * w0.z + a0.w * w0.w
                + a1.x * w1.x + a1.y * w1.y + a1.z * w1.z + a1.w * w1.w;
#pragma unroll
        for (int off = 32; off; off >>= 1) d += __shfl_down(d, off);
        if (lane == 0) em[row * L_ + l] = d + b_cls[l];
    }
}

// ---------------------------------------------------------------------------
// CRF NLL
// ---------------------------------------------------------------------------
__global__ void __launch_bounds__(64) crf_k(
    const float* __restrict__ em, const int* __restrict__ labels,
    const int* __restrict__ mask, const float* __restrict__ trans,
    const float* __restrict__ startv, const float* __restrict__ endv,
    float* __restrict__ out)
{
    int b = blockIdx.x, lane = threadIdx.x;
    const float* emb_ = em + (size_t)b * T_ * L_;
    const int* lab = labels + (size_t)b * T_;
    const int* msk = mask + (size_t)b * T_;
    __shared__ float alpha[L_];
    __shared__ float trs[81];
    for (int i = lane; i < 81; i += 64) trs[i] = trans[i];
    __syncthreads();

    float np = 0.0f;
    for (int t = 1 + lane; t < T_; t += 64)
        if (msk[t]) np += trs[lab[t - 1] * L_ + lab[t]] + emb_[(size_t)t * L_ + lab[t]];
    int mc = 0;
    for (int t = lane; t < T_; t += 64) mc += (msk[t] != 0);
#pragma unroll
    for (int off = 32; off; off >>= 1) {
        np += __shfl_down(np, off);
        mc += __shfl_down(mc, off);
    }
    float num = 0.0f;
    if (lane == 0) {
        int last = mc - 1;
        num = np + startv[lab[0]] + emb_[lab[0]] + endv[lab[last]];
    }

    if (lane < L_) alpha[lane] = startv[lane] + emb_[lane];
    __syncthreads();
    for (int t = 1; t < T_; ++t) {
        float na = 0.0f;
        if (lane < L_) {
            float m = -1e30f;
#pragma unroll
            for (int i = 0; i < L_; ++i) m = fmaxf(m, alpha[i] + trs[i * L_ + lane]);
            float s = 0.0f;
#pragma unroll
            for (int i = 0; i < L_; ++i) s += __expf(alpha[i] + trs[i * L_ + lane] - m);
            na = m + __logf(s) + emb_[(size_t)t * L_ + lane];
            if (!msk[t]) na = alpha[lane];
        }
        __syncthreads();
        if (lane < L_) alpha[lane] = na;
        __syncthreads();
    }
    float v = (lane < L_) ? alpha[lane] + endv[lane] : -1e30f;
    float m = v;
#pragma unroll
    for (int off = 32; off; off >>= 1) m = fmaxf(m, __shfl_xor(m, off));
    float s = (lane < L_) ? __expf(v - m) : 0.0f;
#pragma unroll
    for (int off = 32; off; off >>= 1) s += __shfl_xor(s, off);
    if (lane == 0) {
        float logZ = m + __logf(s);
        atomicAdd(out, (logZ - num) / (float)B_);
    }
}

__global__ void zero_out_k(float* out) { out[0] = 0.0f; }
__global__ void ws_fail_k(float* out, float v) { out[0] = v; }

// ---------------------------------------------------------------------------
extern "C" void kernel_launch(void* const* d_in, const int* in_sizes, int n_in,
                              void* d_out, int out_size, void* d_ws, size_t ws_size,
                              hipStream_t stream)
{
    const int*   ids    = (const int*)  d_in[0];
    const int*   amask  = (const int*)  d_in[1];
    const int*   labels = (const int*)  d_in[2];
    const float* emb    = (const float*)d_in[3];
    const float* w_ih_f = (const float*)d_in[4];
    const float* w_hh_f = (const float*)d_in[5];
    const float* b_ih_f = (const float*)d_in[6];
    const float* b_hh_f = (const float*)d_in[7];
    const float* w_ih_b = (const float*)d_in[8];
    const float* w_hh_b = (const float*)d_in[9];
    const float* b_ih_b = (const float*)d_in[10];
    const float* b_hh_b = (const float*)d_in[11];
    const float* w_cls  = (const float*)d_in[12];
    const float* b_cls  = (const float*)d_in[13];
    const float* trans  = (const float*)d_in[14];
    const float* startv = (const float*)d_in[15];
    const float* endv   = (const float*)d_in[16];
    float* out = (float*)d_out;

    // workspace layout
    size_t o_xg   = 0;                                   // bf16 xg: 128 MB
    size_t o_bias = o_xg + (size_t)NROW * NG * 2;
    size_t o_h    = o_bias + 2048 * 4;
    size_t o_em   = o_h + (size_t)2 * B_ * T_ * H_ * 4;  // 64 MB
    size_t o_hc   = o_em + (size_t)NROW * L_ * 4;
    size_t o_cnt  = o_hc + (size_t)2 * 8 * 1024 * 8;     // h_cur 128 KB (ull)
    size_t total  = o_cnt + (size_t)8 * 512 * 4;         // cnt 16 KB

    if (ws_size < total) {
        ws_fail_k<<<1, 1, 0, stream>>>(out, -1.0e8f - (float)(ws_size >> 20));
        return;
    }

    unsigned short* xg        = (unsigned short*)((char*)d_ws + o_xg);
    float* bias               = (float*)((char*)d_ws + o_bias);
    float* h_all              = (float*)((char*)d_ws + o_h);
    float* em                 = (float*)((char*)d_ws + o_em);
    unsigned long long* h_cur = (unsigned long long*)((char*)d_ws + o_hc);
    int* cnt                  = (int*)((char*)d_ws + o_cnt);

    bias_k<<<8, 256, 0, stream>>>(b_ih_f, b_hh_f, b_ih_b, b_hh_b, bias);
    zero_flags<<<16, 256, 0, stream>>>(cnt);
    xg_gemm<<<dim3(NROW / BM, NG / BN), 256, 0, stream>>>(emb, ids, w_ih_f, w_ih_b, bias, xg);
    lstm_mfma<<<32, 256, 0, stream>>>(xg, w_hh_f, w_hh_b, h_all, h_cur, cnt);
    emis_k<<<NROW / 4, 256, 0, stream>>>(h_all, w_cls, b_cls, em);
    zero_out_k<<<1, 1, 0, stream>>>(out);
    crf_k<<<B_, 64, 0, stream>>>(em, labels, amask, trans, startv, endv, out);
}

// Round 5
// 1887.920 us; speedup vs baseline: 2.5773x; 1.4326x over previous
//
#include <hip/hip_runtime.h>
#include <hip/hip_bf16.h>

// Problem constants
#define B_   64
#define T_   512
#define EMB_ 256
#define H_   256          // hidden per direction
#define L_   9
#define NROW (B_*T_)      // 32768
#define NG   2048         // both directions' gates

typedef __attribute__((ext_vector_type(8))) short bf16x8;
typedef __attribute__((ext_vector_type(4))) float f32x4;

__device__ __forceinline__ float bf2f(unsigned short u) {
    union { unsigned int i; float f; } c; c.i = ((unsigned int)u) << 16; return c.f;
}
__device__ __forceinline__ unsigned int f2bf(float f) {
    union { unsigned int i; float f; } c; c.f = f;
    unsigned int i = c.i;
    return (i + 0x7FFFu + ((i >> 16) & 1u)) >> 16;
}
__device__ __forceinline__ float sigmf(float x) { return 1.0f / (1.0f + __expf(-x)); }
__device__ __forceinline__ float tanh_fast(float x) {
    return 2.0f / (1.0f + __expf(-2.0f * x)) - 1.0f;
}

// ---------------------------------------------------------------------------
// bias[n] = b_ih + b_hh (both dirs)
// ---------------------------------------------------------------------------
__global__ void __launch_bounds__(256) bias_k(
    const float* __restrict__ bihf, const float* __restrict__ bhhf,
    const float* __restrict__ bihb, const float* __restrict__ bhhb,
    float* __restrict__ bias)
{
    int i = blockIdx.x * 256 + threadIdx.x;   // 0..2047
    if (i < 1024) bias[i] = bihf[i] + bhhf[i];
    else          bias[i] = bihb[i - 1024] + bhhb[i - 1024];
}

__global__ void __launch_bounds__(256) zero_flags(int* __restrict__ flags)
{
    flags[blockIdx.x * 256 + threadIdx.x] = 0;   // 64 blocks -> 16384 ints
}

// ---------------------------------------------------------------------------
// xg GEMM: xg[row][n] = sum_k emb[ids[row]][k] * w(n)[k] + bias[n]  (bf16 out)
// ---------------------------------------------------------------------------
#define BM 128
#define BN 128
#define BK 16
__global__ void __launch_bounds__(256) xg_gemm(
    const float* __restrict__ emb, const int* __restrict__ ids,
    const float* __restrict__ w_f, const float* __restrict__ w_b,
    const float* __restrict__ bias, unsigned short* __restrict__ xg)
{
    __shared__ float As[BK][BM];
    __shared__ float Bs[BK][BN];
    __shared__ int rowtok[BM];
    int tid = threadIdx.x;
    int row0 = blockIdx.x * BM;
    int col0 = blockIdx.y * BN;
    if (tid < BM) rowtok[tid] = ids[row0 + tid];
    __syncthreads();

    int tx = tid & 15, ty = tid >> 4;
    float acc[8][8];
#pragma unroll
    for (int i = 0; i < 8; ++i)
#pragma unroll
        for (int j = 0; j < 8; ++j) acc[i][j] = 0.0f;

    for (int k0 = 0; k0 < EMB_; k0 += BK) {
#pragma unroll
        for (int l = 0; l < 2; ++l) {
            int idx = tid + l * 256;
            int r  = idx >> 2;
            int kc = (idx & 3) * 4;
            const float* src = emb + (size_t)rowtok[r] * EMB_ + k0 + kc;
            float4 v = *(const float4*)src;
            As[kc + 0][r] = v.x; As[kc + 1][r] = v.y;
            As[kc + 2][r] = v.z; As[kc + 3][r] = v.w;
        }
#pragma unroll
        for (int l = 0; l < 2; ++l) {
            int idx = tid + l * 256;
            int c  = idx >> 2;
            int kc = (idx & 3) * 4;
            int n  = col0 + c;
            const float* wr = (n < 1024) ? (w_f + (size_t)n * EMB_)
                                         : (w_b + (size_t)(n - 1024) * EMB_);
            float4 v = *(const float4*)(wr + k0 + kc);
            Bs[kc + 0][c] = v.x; Bs[kc + 1][c] = v.y;
            Bs[kc + 2][c] = v.z; Bs[kc + 3][c] = v.w;
        }
        __syncthreads();
#pragma unroll
        for (int k = 0; k < BK; ++k) {
            float a[8], b[8];
            *(float4*)&a[0] = *(float4*)&As[k][ty * 8];
            *(float4*)&a[4] = *(float4*)&As[k][ty * 8 + 4];
            *(float4*)&b[0] = *(float4*)&Bs[k][tx * 8];
            *(float4*)&b[4] = *(float4*)&Bs[k][tx * 8 + 4];
#pragma unroll
            for (int i = 0; i < 8; ++i)
#pragma unroll
                for (int j = 0; j < 8; ++j) acc[i][j] += a[i] * b[j];
        }
        __syncthreads();
    }
#pragma unroll
    for (int i = 0; i < 8; ++i) {
        size_t row = (size_t)row0 + ty * 8 + i;
#pragma unroll
        for (int j4 = 0; j4 < 2; ++j4) {
            int nb = col0 + tx * 8 + j4 * 4;
            ushort4 o;
            o.x = (unsigned short)f2bf(acc[i][j4 * 4 + 0] + bias[nb + 0]);
            o.y = (unsigned short)f2bf(acc[i][j4 * 4 + 1] + bias[nb + 1]);
            o.z = (unsigned short)f2bf(acc[i][j4 * 4 + 2] + bias[nb + 2]);
            o.w = (unsigned short)f2bf(acc[i][j4 * 4 + 3] + bias[nb + 3]);
            *(ushort4*)(xg + row * NG + nb) = o;
        }
    }
}

// ---------------------------------------------------------------------------
// Persistent cluster LSTM, register-resident weights + MFMA, K-split waves.
// 32 blocks x 256 threads. cluster = bid & 7 = (dir, 16-batch group);
// 4 blocks per cluster; block blk owns output h-dims [blk*64, blk*64+64).
// Wave kq computes ALL 4 gates' partial sums over k in [kq*64, kq*64+64),
// so wave kq depends on exactly one producer block (blk == kq) of its
// cluster; the self-slice (kq == blk) needs no poll at all (own block's
// stores drained at the previous step's barrier).
// h exchange = h history buffer (bf16, indexed by t -> no reuse, no WAR).
// All cross-block traffic relaxed agent-scope atomics (cache-bypassing).
// Ordering: __syncthreads vmcnt-drain before flag store; consumer loads h
// only after observing the flag (MALL arrival order argument).
// ---------------------------------------------------------------------------
__global__ void __launch_bounds__(256, 1) lstm_mfma(
    const unsigned short* __restrict__ xg,
    const float* __restrict__ w_hh_f, const float* __restrict__ w_hh_b,
    unsigned long long* __restrict__ h_hist,  // [2][64][512][64] ull (4 bf16 each)
    int* __restrict__ flags)                  // [8 cluster][4 blk][512 step]
{
    const int bid = blockIdx.x;      // 0..31
    const int cluster = bid & 7;
    const int blk = bid >> 3;        // 0..3  (output h-slice owner)
    const int dir = cluster >> 2;
    const int bbase = (cluster & 3) * 16;
    const int j0 = blk * 64;
    const int tid = threadIdx.x;
    const int kq = tid >> 6;         // wave's K-slice == producer block id
    const int l = tid & 63;
    const int l15 = l & 15, lq = l >> 4;

    const float* whh = dir ? w_hh_b : w_hh_f;

    // Stationary B fragments:
    // bfrag[g][nt][kt][e] = w[(g*256 + j0 + nt*16 + l15)][kq*64 + kt*32 + lq*8 + e]
    bf16x8 bfrag[4][4][2];
#pragma unroll
    for (int g = 0; g < 4; ++g)
#pragma unroll
        for (int nt = 0; nt < 4; ++nt) {
            const float* wr = whh + (size_t)(g * 256 + j0 + nt * 16 + l15) * 256
                                  + kq * 64 + lq * 8;
#pragma unroll
            for (int kt = 0; kt < 2; ++kt) {
                bf16x8 f;
#pragma unroll
                for (int e = 0; e < 8; ++e)
                    f[e] = (short)f2bf(wr[kt * 32 + e]);
                bfrag[g][nt][kt] = f;
            }
        }

    __shared__ float pg[4][4][16][68];   // [kq][gate][b][j-local], 16B-aligned rows

    int* myflag = flags + (cluster * 4 + blk) * 512;
    const int* pollflag = flags + (cluster * 4 + kq) * 512;

    // cell-update ownership: b = bbase + ub, j = j0 + jj0 + q
    const int ub = tid >> 4, jj0 = (tid & 15) * 4;
    float cst[4] = {0.f, 0.f, 0.f, 0.f};

    const size_t hrow_rd = (size_t)(dir * 64 + bbase + l15) * 512;  // + t -> *64 words
    const size_t hrow_wr = (size_t)(dir * 64 + bbase + ub) * 512;
    const unsigned short* xbase = xg + (size_t)(bbase + ub) * T_ * NG + dir * 1024 + j0 + jj0;

    for (int s = 0; s < T_; ++s) {
        const int t = dir ? (T_ - 1 - s) : s;

        // xg loads for this step: issued BEFORE the poll, consumed at combine.
        ushort4 xq[4];
#pragma unroll
        for (int g = 0; g < 4; ++g)
            xq[g] = *(const ushort4*)(xbase + (size_t)t * NG + g * 256);

        f32x4 acc[4][4];
#pragma unroll
        for (int g = 0; g < 4; ++g)
#pragma unroll
            for (int nt = 0; nt < 4; ++nt)
                acc[g][nt] = (f32x4){0.f, 0.f, 0.f, 0.f};

        if (s > 0) {
            if (kq != blk) {   // wave-uniform poll, all lanes same address
                while (__hip_atomic_load(&pollflag[s - 1], __ATOMIC_RELAXED,
                                         __HIP_MEMORY_SCOPE_AGENT) == 0)
                    __builtin_amdgcn_s_sleep(1);
            }
            const int tp = dir ? (t + 1) : (t - 1);
            const unsigned long long* hb =
                h_hist + (hrow_rd + tp) * 64 + kq * 16 + lq * 2;
            bf16x8 af[2];
#pragma unroll
            for (int kt = 0; kt < 2; ++kt) {
                union { unsigned long long u[2]; bf16x8 v; } a;
                a.u[0] = __hip_atomic_load(hb + kt * 8 + 0, __ATOMIC_RELAXED,
                                           __HIP_MEMORY_SCOPE_AGENT);
                a.u[1] = __hip_atomic_load(hb + kt * 8 + 1, __ATOMIC_RELAXED,
                                           __HIP_MEMORY_SCOPE_AGENT);
                af[kt] = a.v;
            }
#pragma unroll
            for (int g = 0; g < 4; ++g)
#pragma unroll
                for (int nt = 0; nt < 4; ++nt)
#pragma unroll
                    for (int kt = 0; kt < 2; ++kt)
                        acc[g][nt] = __builtin_amdgcn_mfma_f32_16x16x32_bf16(
                            af[kt], bfrag[g][nt][kt], acc[g][nt], 0, 0, 0);
        }

        // partial gates -> LDS: pg[kq][g][b = lq*4+r][nt*16 + l15]
#pragma unroll
        for (int g = 0; g < 4; ++g)
#pragma unroll
            for (int nt = 0; nt < 4; ++nt)
#pragma unroll
                for (int r = 0; r < 4; ++r)
                    pg[kq][g][lq * 4 + r][nt * 16 + l15] = acc[g][nt][r];
        __syncthreads();

        // combine partials + xg, cell update (4 h-values per thread)
        union F4 { float4 v; float a[4]; };
        F4 gv[4];
#pragma unroll
        for (int g = 0; g < 4; ++g) {
            float4 v = make_float4(bf2f(xq[g].x), bf2f(xq[g].y),
                                   bf2f(xq[g].z), bf2f(xq[g].w));
#pragma unroll
            for (int q2 = 0; q2 < 4; ++q2) {
                const float4 p = *(const float4*)&pg[q2][g][ub][jj0];
                v.x += p.x; v.y += p.y; v.z += p.z; v.w += p.w;
            }
            gv[g].v = v;
        }
        float hv[4];
#pragma unroll
        for (int q = 0; q < 4; ++q) {
            float ci = sigmf(gv[1].a[q]) * cst[q] + sigmf(gv[0].a[q]) * tanh_fast(gv[2].a[q]);
            cst[q] = ci;
            hv[q] = sigmf(gv[3].a[q]) * tanh_fast(ci);
        }

        // pack 4 bf16 -> one 8B relaxed agent store into the history buffer
        unsigned int lo = f2bf(hv[0]) | (f2bf(hv[1]) << 16);
        unsigned int hi = f2bf(hv[2]) | (f2bf(hv[3]) << 16);
        unsigned long long pw = (unsigned long long)lo | ((unsigned long long)hi << 32);
        __hip_atomic_store(&h_hist[(hrow_wr + t) * 64 + ((j0 + jj0) >> 2)], pw,
                           __ATOMIC_RELAXED, __HIP_MEMORY_SCOPE_AGENT);
        __syncthreads();   // vmcnt(0) drain: all h stores ACKed before flag
        if (tid == 0)
            __hip_atomic_store(&myflag[s], 1, __ATOMIC_RELAXED,
                               __HIP_MEMORY_SCOPE_AGENT);
    }
}

// ---------------------------------------------------------------------------
// Emissions (reads bf16 h history)
// ---------------------------------------------------------------------------
__global__ void __launch_bounds__(256) emis_k(
    const unsigned short* __restrict__ h_hist, const float* __restrict__ w_cls,
    const float* __restrict__ b_cls, float* __restrict__ em)
{
    int wid = threadIdx.x >> 6, lane = threadIdx.x & 63;
    size_t row = (size_t)blockIdx.x * 4 + wid;       // b*T + t
    const unsigned short* hf = h_hist + row * 256;
    const unsigned short* hb = h_hist + (size_t)64 * 512 * 256 + row * 256;
    ushort4 u0 = *(const ushort4*)(hf + 4 * lane);
    ushort4 u1 = *(const ushort4*)(hb + 4 * lane);
    float a0x = bf2f(u0.x), a0y = bf2f(u0.y), a0z = bf2f(u0.z), a0w = bf2f(u0.w);
    float a1x = bf2f(u1.x), a1y = bf2f(u1.y), a1z = bf2f(u1.z), a1w = bf2f(u1.w);
#pragma unroll
    for (int l = 0; l < L_; ++l) {
        const float* wr = w_cls + (size_t)l * 512;
        float4 w0 = *(const float4*)(wr + 4 * lane);
        float4 w1 = *(const float4*)(wr + 256 + 4 * lane);
        float d = a0x * w0.x + a0y * w0.y + a0z * w0.z + a0w * w0.w
                + a1x * w1.x + a1y * w1.y + a1z * w1.z + a1w * w1.w;
#pragma unroll
        for (int off = 32; off; off >>= 1) d += __shfl_down(d, off);
        if (lane == 0) em[row * L_ + l] = d + b_cls[l];
    }
}

// ---------------------------------------------------------------------------
// CRF NLL
// ---------------------------------------------------------------------------
__global__ void __launch_bounds__(64) crf_k(
    const float* __restrict__ em, const int* __restrict__ labels,
    const int* __restrict__ mask, const float* __restrict__ trans,
    const float* __restrict__ startv, const float* __restrict__ endv,
    float* __restrict__ out)
{
    int b = blockIdx.x, lane = threadIdx.x;
    const float* emb_ = em + (size_t)b * T_ * L_;
    const int* lab = labels + (size_t)b * T_;
    const int* msk = mask + (size_t)b * T_;
    __shared__ float alpha[L_];
    __shared__ float trs[81];
    for (int i = lane; i < 81; i += 64) trs[i] = trans[i];
    __syncthreads();

    float np = 0.0f;
    for (int t = 1 + lane; t < T_; t += 64)
        if (msk[t]) np += trs[lab[t - 1] * L_ + lab[t]] + emb_[(size_t)t * L_ + lab[t]];
    int mc = 0;
    for (int t = lane; t < T_; t += 64) mc += (msk[t] != 0);
#pragma unroll
    for (int off = 32; off; off >>= 1) {
        np += __shfl_down(np, off);
        mc += __shfl_down(mc, off);
    }
    float num = 0.0f;
    if (lane == 0) {
        int last = mc - 1;
        num = np + startv[lab[0]] + emb_[lab[0]] + endv[lab[last]];
    }

    if (lane < L_) alpha[lane] = startv[lane] + emb_[lane];
    __syncthreads();
    for (int t = 1; t < T_; ++t) {
        float na = 0.0f;
        if (lane < L_) {
            float m = -1e30f;
#pragma unroll
            for (int i = 0; i < L_; ++i) m = fmaxf(m, alpha[i] + trs[i * L_ + lane]);
            float s = 0.0f;
#pragma unroll
            for (int i = 0; i < L_; ++i) s += __expf(alpha[i] + trs[i * L_ + lane] - m);
            na = m + __logf(s) + emb_[(size_t)t * L_ + lane];
            if (!msk[t]) na = alpha[lane];
        }
        __syncthreads();
        if (lane < L_) alpha[lane] = na;
        __syncthreads();
    }
    float v = (lane < L_) ? alpha[lane] + endv[lane] : -1e30f;
    float m = v;
#pragma unroll
    for (int off = 32; off; off >>= 1) m = fmaxf(m, __shfl_xor(m, off));
    float s = (lane < L_) ? __expf(v - m) : 0.0f;
#pragma unroll
    for (int off = 32; off; off >>= 1) s += __shfl_xor(s, off);
    if (lane == 0) {
        float logZ = m + __logf(s);
        atomicAdd(out, (logZ - num) / (float)B_);
    }
}

__global__ void zero_out_k(float* out) { out[0] = 0.0f; }
__global__ void ws_fail_k(float* out, float v) { out[0] = v; }

// ---------------------------------------------------------------------------
extern "C" void kernel_launch(void* const* d_in, const int* in_sizes, int n_in,
                              void* d_out, int out_size, void* d_ws, size_t ws_size,
                              hipStream_t stream)
{
    const int*   ids    = (const int*)  d_in[0];
    const int*   amask  = (const int*)  d_in[1];
    const int*   labels = (const int*)  d_in[2];
    const float* emb    = (const float*)d_in[3];
    const float* w_ih_f = (const float*)d_in[4];
    const float* w_hh_f = (const float*)d_in[5];
    const float* b_ih_f = (const float*)d_in[6];
    const float* b_hh_f = (const float*)d_in[7];
    const float* w_ih_b = (const float*)d_in[8];
    const float* w_hh_b = (const float*)d_in[9];
    const float* b_ih_b = (const float*)d_in[10];
    const float* b_hh_b = (const float*)d_in[11];
    const float* w_cls  = (const float*)d_in[12];
    const float* b_cls  = (const float*)d_in[13];
    const float* trans  = (const float*)d_in[14];
    const float* startv = (const float*)d_in[15];
    const float* endv   = (const float*)d_in[16];
    float* out = (float*)d_out;

    // workspace layout
    size_t o_xg    = 0;                                    // bf16 xg: 128 MB
    size_t o_bias  = o_xg + (size_t)NROW * NG * 2;
    size_t o_hh    = o_bias + 2048 * 4;                    // h_hist: 32 MB
    size_t o_em    = o_hh + (size_t)2 * B_ * T_ * 64 * 8;
    size_t o_fl    = o_em + (size_t)NROW * L_ * 4;         // flags: 64 KB
    size_t total   = o_fl + (size_t)8 * 4 * 512 * 4;

    if (ws_size < total) {
        ws_fail_k<<<1, 1, 0, stream>>>(out, -1.0e8f - (float)(ws_size >> 20));
        return;
    }

    unsigned short* xg         = (unsigned short*)((char*)d_ws + o_xg);
    float* bias                = (float*)((char*)d_ws + o_bias);
    unsigned long long* h_hist = (unsigned long long*)((char*)d_ws + o_hh);
    float* em                  = (float*)((char*)d_ws + o_em);
    int* flags                 = (int*)((char*)d_ws + o_fl);

    bias_k<<<8, 256, 0, stream>>>(b_ih_f, b_hh_f, b_ih_b, b_hh_b, bias);
    zero_flags<<<64, 256, 0, stream>>>(flags);
    xg_gemm<<<dim3(NROW / BM, NG / BN), 256, 0, stream>>>(emb, ids, w_ih_f, w_ih_b, bias, xg);
    lstm_mfma<<<32, 256, 0, stream>>>(xg, w_hh_f, w_hh_b, h_hist, flags);
    emis_k<<<NROW / 4, 256, 0, stream>>>((const unsigned short*)h_hist, w_cls, b_cls, em);
    zero_out_k<<<1, 1, 0, stream>>>(out);
    crf_k<<<B_, 64, 0, stream>>>(em, labels, amask, trans, startv, endv, out);
}